// Round 4
// baseline (552.527 us; speedup 1.0000x reference)
//
#include <hip/hip_runtime.h>
#include <hip/hip_bf16.h>

#define N_NODES 50000
#define E_EDGES 800000
#define F_DIM 128
#define D_DIM 32
#define CUTOFF 5.0f
#define PI_F 3.14159265358979f

__device__ __forceinline__ float swishf(float x) { return x / (1.0f + expf(-x)); }

// wave-broadcast of lane `lane`'s value (v_readlane -> SGPR, VALU pipe)
__device__ __forceinline__ float rl(float v, int lane) {
  return __int_as_float(__builtin_amdgcn_readlane(__float_as_int(v), lane));
}

// ---------------------------------------------------------------------------
// Fused node MLP, one branch per blockIdx.y.
// Block = 512 (8 waves), 4 rows/wave -> 32 rows/block, grid.x = 1563.
// W1 staged per 64-col half, transposed+XOR-swizzled in LDS -> b128 reads.
// W2 transposed+swizzled, resident. x and h live in registers; k-broadcast
// via v_readlane. LDS = 48 KB -> 3 blocks/CU.
// Output layout: qq[row*64 + 2*c + branch]  (q/q2 interleaved per element).
// ---------------------------------------------------------------------------
__global__ __launch_bounds__(512)
void node_mlp_fused(const float* __restrict__ x,
                    const float* __restrict__ W1a, const float* __restrict__ b1a,
                    const float* __restrict__ W2a, const float* __restrict__ b2a,
                    const float* __restrict__ W1b, const float* __restrict__ b1b,
                    const float* __restrict__ W2b, const float* __restrict__ b2b,
                    float* __restrict__ qq) {
  __shared__ float sW1[64 * F_DIM];     // 32 KB: [c' (64 cols of half)][k sw]
  __shared__ float sW2[D_DIM * F_DIM];  // 16 KB: [c (32 cols)][k swizzled]

  const int br = blockIdx.y;
  const float* W1 = br ? W1b : W1a;
  const float* b1 = br ? b1b : b1a;
  const float* W2 = br ? W2b : W2a;
  const float* b2 = br ? b2b : b2a;

  const int t = threadIdx.x;
  const int w = t >> 6, l = t & 63;

  // stage swizzled W2: chunk id = (k4, c); store W2[4k4+j][c] at c*128+4*(k4^(c&7))+j
  for (int id = t; id < D_DIM * 32; id += 512) {
    const int c  = id & 31;
    const int k4 = id >> 5;
    const int sl = k4 ^ (c & 7);
#pragma unroll
    for (int j = 0; j < 4; ++j)
      sW2[c * 128 + 4 * sl + j] = W2[(4 * k4 + j) * D_DIM + c];
  }

  // x rows in registers: xr[r][jj] = x[row_r][jj*64 + l]
  const int rowBase = blockIdx.x * 32 + w * 4;
  float xr[4][2];
#pragma unroll
  for (int r = 0; r < 4; ++r) {
    const int row = min(rowBase + r, N_NODES - 1);
    xr[r][0] = x[(size_t)row * F_DIM + l];
    xr[r][1] = x[(size_t)row * F_DIM + 64 + l];
  }
  float rb1[2];
  rb1[0] = b1[l];
  rb1[1] = b1[64 + l];

  float hreg[2][4];  // [half=col>>6][row]: h[row][half*64 + l]

  // ----- layer 1, per 64-col half -----
#pragma unroll
  for (int half = 0; half < 2; ++half) {
    __syncthreads();  // previous half's readers done (and sW2/x staging settled)
    for (int id = t; id < 64 * 32; id += 512) {  // (k4, c') chunks
      const int c  = id & 63;
      const int k4 = id >> 6;
      const int sl = k4 ^ (c & 7);
#pragma unroll
      for (int j = 0; j < 4; ++j)
        sW1[c * 128 + 4 * sl + j] = W1[(4 * k4 + j) * F_DIM + half * 64 + c];
    }
    __syncthreads();

    float acc[4] = {rb1[half], rb1[half], rb1[half], rb1[half]};
    const int wbase = l * 128;
    const int wxor  = l & 7;
#pragma unroll
    for (int k4 = 0; k4 < 32; ++k4) {
      const float4 wv = *(const float4*)&sW1[wbase + 4 * (k4 ^ wxor)];
      const float* wvp = &wv.x;
#pragma unroll
      for (int j = 0; j < 4; ++j) {
        const int k = k4 * 4 + j;
        const float wj = wvp[j];
#pragma unroll
        for (int r = 0; r < 4; ++r)
          acc[r] += rl(xr[r][k >> 6], k & 63) * wj;
      }
    }
#pragma unroll
    for (int r = 0; r < 4; ++r) hreg[half][r] = swishf(acc[r]);
  }

  // ----- layer 2: lane = (row-slot g = l>>5, col c = l&31), rows {g, g+2} -----
  const int g = l >> 5;
  const int c = l & 31;
  float acc2[2];
  acc2[0] = acc2[1] = b2[c];
  const int w2base = c * 128;
  const int w2xor  = c & 7;
#pragma unroll
  for (int k4 = 0; k4 < 32; ++k4) {
    const float4 wv = *(const float4*)&sW2[w2base + 4 * (k4 ^ w2xor)];
    const float* wvp = &wv.x;
#pragma unroll
    for (int j = 0; j < 4; ++j) {
      const int k  = k4 * 4 + j;
      const int jj = k >> 6, kl = k & 63;
      const float h0 = rl(hreg[jj][0], kl);
      const float h1 = rl(hreg[jj][1], kl);
      const float h2 = rl(hreg[jj][2], kl);
      const float h3 = rl(hreg[jj][3], kl);
      const float wj = wvp[j];
      acc2[0] += (g ? h1 : h0) * wj;  // row rowBase+g
      acc2[1] += (g ? h3 : h2) * wj;  // row rowBase+g+2
    }
  }
  const int ra = rowBase + g;
  const int rb_ = rowBase + g + 2;
  if (ra  < N_NODES) qq[(size_t)ra  * 64 + 2 * c + br] = swishf(acc2[0]);
  if (rb_ < N_NODES) qq[(size_t)rb_ * 64 + 2 * c + br] = swishf(acc2[1]);
}

// ---------------------------------------------------------------------------
// CSR build: histogram of dst over cutoff-surviving edges
// ---------------------------------------------------------------------------
__global__ __launch_bounds__(256)
void edge_hist(const float* __restrict__ rij, const int* __restrict__ dst,
               int* __restrict__ deg) {
  const int e = blockIdx.x * 256 + threadIdx.x;
  if (e >= E_EDGES) return;
  if (rij[e] < CUTOFF) atomicAdd(&deg[dst[e]], 1);
}

// Exclusive scan over deg[N] -> row_start[N+1] and cursor[N] (single block)
__global__ __launch_bounds__(1024)
void scan_offsets(const int* __restrict__ deg, int* __restrict__ row_start,
                  int* __restrict__ cursor) {
  __shared__ int part[1024];
  const int t = threadIdx.x;
  const int CH = (N_NODES + 1023) / 1024;  // 49
  const int lo = t * CH;
  const int hi = min(lo + CH, N_NODES);
  int s = 0;
  for (int i = lo; i < hi; ++i) s += deg[i];
  part[t] = s;
  __syncthreads();
  for (int off = 1; off < 1024; off <<= 1) {
    const int v = part[t];
    const int u = (t >= off) ? part[t - off] : 0;
    __syncthreads();
    part[t] = v + u;
    __syncthreads();
  }
  int excl = (t == 0) ? 0 : part[t - 1];
  for (int i = lo; i < hi; ++i) {
    row_start[i] = excl;
    cursor[i] = excl;
    excl += deg[i];
  }
  if (t == 1023) row_start[N_NODES] = part[1023];
}

// Reorder surviving edges into per-dst contiguous records:
// rec = (c*vx, c*vy, c*vz, bitcast(src))
__global__ __launch_bounds__(256)
void edge_reorder(const float* __restrict__ rij, const float* __restrict__ vij,
                  const int* __restrict__ src, const int* __restrict__ dst,
                  int* __restrict__ cursor, float4* __restrict__ recs) {
  const int e = blockIdx.x * 256 + threadIdx.x;
  if (e >= E_EDGES) return;
  const float r = rij[e];
  if (r >= CUTOFF) return;
  const float c = 0.5f * (cosf(r * (PI_F / CUTOFF)) + 1.0f);
  const int pos = atomicAdd(&cursor[dst[e]], 1);
  recs[pos] = make_float4(c * vij[3 * e + 0], c * vij[3 * e + 1],
                          c * vij[3 * e + 2], __int_as_float(src[e]));
}

// ---------------------------------------------------------------------------
// Gather + cross + mix: 32 lanes per node (one per d). 4-edge batches to
// break the rec->q dependent-load chain; qq is (q,q2) interleaved float2.
// ---------------------------------------------------------------------------
__global__ __launch_bounds__(256)
void gather_out(const int* __restrict__ row_start, const float4* __restrict__ recs,
                const float2* __restrict__ qq,
                const float* __restrict__ w_mix, const float* __restrict__ b_mix,
                float* __restrict__ out) {
  const int tid = blockIdx.x * 256 + threadIdx.x;  // = n*32 + d
  const int n = tid >> 5;
  const int d = tid & 31;
  if (n >= N_NODES) return;

  const int s0 = row_start[n];
  const int s1 = row_start[n + 1];

  float ax = 0.f, ay = 0.f, az = 0.f, bx = 0.f, by = 0.f, bz = 0.f;
  for (int i = s0; i < s1; i += 4) {
    const int i1 = min(i + 1, s1 - 1);
    const int i2 = min(i + 2, s1 - 1);
    const int i3 = min(i + 3, s1 - 1);
    float4 rc0 = recs[i];
    float4 rc1 = recs[i1];
    float4 rc2 = recs[i2];
    float4 rc3 = recs[i3];
    float2 p0 = qq[__float_as_int(rc0.w) * 32 + d];
    float2 p1 = qq[__float_as_int(rc1.w) * 32 + d];
    float2 p2 = qq[__float_as_int(rc2.w) * 32 + d];
    float2 p3 = qq[__float_as_int(rc3.w) * 32 + d];
    const float m1 = (i + 1 < s1) ? 1.f : 0.f;
    const float m2 = (i + 2 < s1) ? 1.f : 0.f;
    const float m3 = (i + 3 < s1) ? 1.f : 0.f;
    p1.x *= m1; p1.y *= m1;
    p2.x *= m2; p2.y *= m2;
    p3.x *= m3; p3.y *= m3;

    ax += rc0.x * p0.x + rc1.x * p1.x + rc2.x * p2.x + rc3.x * p3.x;
    ay += rc0.y * p0.x + rc1.y * p1.x + rc2.y * p2.x + rc3.y * p3.x;
    az += rc0.z * p0.x + rc1.z * p1.x + rc2.z * p2.x + rc3.z * p3.x;
    bx += rc0.x * p0.y + rc1.x * p1.y + rc2.x * p2.y + rc3.x * p3.y;
    by += rc0.y * p0.y + rc1.y * p1.y + rc2.y * p2.y + rc3.y * p3.y;
    bz += rc0.z * p0.y + rc1.z * p1.y + rc2.z * p2.y + rc3.z * p3.y;
  }

  const float cx = ay * bz - az * by;
  const float cy = az * bx - ax * bz;
  const float cz = ax * by - ay * bx;

  const float w0 = w_mix[0], w1 = w_mix[1], w2 = w_mix[2];
  const float bm = b_mix[0];

  const size_t base = (size_t)tid * 3;
  out[base + 0] = ax * w0 + bx * w1 + cx * w2 + bm;
  out[base + 1] = ay * w0 + by * w1 + cy * w2 + bm;
  out[base + 2] = az * w0 + bz * w1 + cz * w2 + bm;
}

// ---------------------------------------------------------------------------
extern "C" void kernel_launch(void* const* d_in, const int* in_sizes, int n_in,
                              void* d_out, int out_size, void* d_ws, size_t ws_size,
                              hipStream_t stream) {
  const float* x     = (const float*)d_in[0];
  const float* rij   = (const float*)d_in[1];
  const float* vij   = (const float*)d_in[2];
  const int*   src   = (const int*)  d_in[3];
  const int*   dst   = (const int*)  d_in[4];
  const float* W1    = (const float*)d_in[5];
  const float* b1    = (const float*)d_in[6];
  const float* W2    = (const float*)d_in[7];
  const float* b2    = (const float*)d_in[8];
  const float* W1b   = (const float*)d_in[9];
  const float* b1b   = (const float*)d_in[10];
  const float* W2b   = (const float*)d_in[11];
  const float* b2b   = (const float*)d_in[12];
  const float* w_mix = (const float*)d_in[13];
  const float* b_mix = (const float*)d_in[14];
  float* out = (float*)d_out;

  // Workspace: recs [E float4] | qq [N*64] | deg [N] | cursor [N] | row_start [N+1]
  float4* recs   = (float4*)d_ws;
  float* qq      = (float*)(recs + E_EDGES);
  int* deg       = (int*)(qq + (size_t)N_NODES * 64);
  int* cursor    = deg + N_NODES;
  int* row_start = cursor + N_NODES;

  hipMemsetAsync(deg, 0, sizeof(int) * N_NODES, stream);

  dim3 mlp_grid((N_NODES + 31) / 32, 2);
  node_mlp_fused<<<mlp_grid, 512, 0, stream>>>(
      x, W1, b1, W2, b2, W1b, b1b, W2b, b2b, qq);

  const int eb = (E_EDGES + 255) / 256;
  edge_hist<<<eb, 256, 0, stream>>>(rij, dst, deg);
  scan_offsets<<<1, 1024, 0, stream>>>(deg, row_start, cursor);
  edge_reorder<<<eb, 256, 0, stream>>>(rij, vij, src, dst, cursor, recs);

  gather_out<<<(N_NODES * D_DIM) / 256, 256, 0, stream>>>(
      row_start, recs, (const float2*)qq, w_mix, b_mix, out);
}

// Round 5
// 350.671 us; speedup vs baseline: 1.5756x; 1.5756x over previous
//
#include <hip/hip_runtime.h>
#include <hip/hip_bf16.h>

#define N_NODES 50000
#define E_EDGES 800000
#define F_DIM 128
#define D_DIM 32
#define CUTOFF 5.0f
#define PI_F 3.14159265358979f
#define SCAN_BLOCKS ((N_NODES + 255) / 256)   // 196

__device__ __forceinline__ float swishf(float x) { return x / (1.0f + expf(-x)); }

// ---------------------------------------------------------------------------
// Fused node MLP, branch = blockIdx.y. Block 256 = 4 waves; 8 rows/wave.
// Layer 1: lane = col (per 64-col half); weights streamed from global (L2-
// resident, coalesced 256 B per k); x read via wave-uniform scalar loads
// (rows are wave-owned) -> every VALU op is an FMA with an SGPR operand.
// Layer 2: h staged in wave-private LDS (no barriers anywhere).
// Output: qq[row*64 + 2*c + br]  (q/q2 interleaved).
// ---------------------------------------------------------------------------
__global__ __launch_bounds__(256)
void node_mlp_fused(const float* __restrict__ x,
                    const float* __restrict__ W1a, const float* __restrict__ b1a,
                    const float* __restrict__ W2a, const float* __restrict__ b2a,
                    const float* __restrict__ W1b, const float* __restrict__ b1b,
                    const float* __restrict__ W2b, const float* __restrict__ b2b,
                    float* __restrict__ qq) {
  __shared__ float sH[4][8][F_DIM];   // 16 KB, wave-private [w] regions

  const int br = blockIdx.y;
  const float* __restrict__ W1 = br ? W1b : W1a;
  const float* __restrict__ b1 = br ? b1b : b1a;
  const float* __restrict__ W2 = br ? W2b : W2a;
  const float* __restrict__ b2 = br ? b2b : b2a;

  const int w = __builtin_amdgcn_readfirstlane(threadIdx.x >> 6);
  const int l = threadIdx.x & 63;
  const int rowBase = (blockIdx.x * 4 + w) * 8;

  // wave-uniform row pointers (tail rows clamped; stores guarded below)
  const float* xr[8];
#pragma unroll
  for (int r = 0; r < 8; ++r)
    xr[r] = x + (size_t)min(rowBase + r, N_NODES - 1) * F_DIM;

  // ----- layer 1: two 64-col halves, lane = col within half -----
#pragma unroll
  for (int half = 0; half < 2; ++half) {
    const int col = half * 64 + l;
    const float binit = b1[col];
    float acc[8];
#pragma unroll
    for (int r = 0; r < 8; ++r) acc[r] = binit;

    const float* Wc = W1 + col;                 // column `col`, stride F_DIM
#pragma unroll 4
    for (int k = 0; k < F_DIM; ++k) {
      const float wk = Wc[(size_t)k * F_DIM];   // coalesced 256 B across wave
#pragma unroll
      for (int r = 0; r < 8; ++r) acc[r] = fmaf(xr[r][k], wk, acc[r]);
    }
#pragma unroll
    for (int r = 0; r < 8; ++r) sH[w][r][col] = swishf(acc[r]);
  }
  // sH[w] is wave-private; in-wave LDS ordering is handled by lgkmcnt.

  // ----- layer 2: lane -> (row-slot g = l>>5, col c = l&31), rows g+2*rr -----
  const int c = l & 31;
  const int g = l >> 5;
  const float b2c = b2[c];
  float acc2[4] = {b2c, b2c, b2c, b2c};

#pragma unroll 2
  for (int k4 = 0; k4 < 32; ++k4) {
    const float w0 = W2[(4 * k4 + 0) * D_DIM + c];
    const float w1 = W2[(4 * k4 + 1) * D_DIM + c];
    const float w2v = W2[(4 * k4 + 2) * D_DIM + c];
    const float w3 = W2[(4 * k4 + 3) * D_DIM + c];
#pragma unroll
    for (int rr = 0; rr < 4; ++rr) {
      const float4 hv = *(const float4*)&sH[w][g + 2 * rr][4 * k4];
      acc2[rr] += hv.x * w0 + hv.y * w1 + hv.z * w2v + hv.w * w3;
    }
  }
#pragma unroll
  for (int rr = 0; rr < 4; ++rr) {
    const int row = rowBase + g + 2 * rr;
    if (row < N_NODES) qq[(size_t)row * 64 + 2 * c + br] = swishf(acc2[rr]);
  }
}

// ---------------------------------------------------------------------------
// CSR build: histogram of dst over cutoff-surviving edges
// ---------------------------------------------------------------------------
__global__ __launch_bounds__(256)
void edge_hist(const float* __restrict__ rij, const int* __restrict__ dst,
               int* __restrict__ deg) {
  const int e = blockIdx.x * 256 + threadIdx.x;
  if (e >= E_EDGES) return;
  if (rij[e] < CUTOFF) atomicAdd(&deg[dst[e]], 1);
}

// --- 3-phase coalesced scan over deg[N] -> row_start[N+1], cursor[N] ---
__global__ __launch_bounds__(256)
void scan_blocksum(const int* __restrict__ deg, int* __restrict__ part) {
  __shared__ int red[256];
  const int t = threadIdx.x;
  const int i = blockIdx.x * 256 + t;
  red[t] = (i < N_NODES) ? deg[i] : 0;
  __syncthreads();
#pragma unroll
  for (int off = 128; off > 0; off >>= 1) {
    if (t < off) red[t] += red[t + off];
    __syncthreads();
  }
  if (t == 0) part[blockIdx.x] = red[0];
}

__global__ __launch_bounds__(256)
void scan_partials(int* __restrict__ part, int* __restrict__ row_start) {
  __shared__ int s[256];
  const int t = threadIdx.x;
  const int v = (t < SCAN_BLOCKS) ? part[t] : 0;
  s[t] = v;
  __syncthreads();
  for (int off = 1; off < 256; off <<= 1) {
    const int u = (t >= off) ? s[t - off] : 0;
    __syncthreads();
    s[t] += u;
    __syncthreads();
  }
  if (t < SCAN_BLOCKS) part[t] = s[t] - v;          // exclusive block offset
  if (t == 255) row_start[N_NODES] = s[255];        // grand total
}

__global__ __launch_bounds__(256)
void scan_write(const int* __restrict__ deg, const int* __restrict__ part,
                int* __restrict__ row_start, int* __restrict__ cursor) {
  __shared__ int s[256];
  const int t = threadIdx.x;
  const int i = blockIdx.x * 256 + t;
  const int v = (i < N_NODES) ? deg[i] : 0;
  s[t] = v;
  __syncthreads();
  for (int off = 1; off < 256; off <<= 1) {
    const int u = (t >= off) ? s[t - off] : 0;
    __syncthreads();
    s[t] += u;
    __syncthreads();
  }
  const int excl = s[t] - v + part[blockIdx.x];
  if (i < N_NODES) { row_start[i] = excl; cursor[i] = excl; }
}

// Reorder surviving edges into per-dst contiguous records:
// rec = (c*vx, c*vy, c*vz, bitcast(src))
__global__ __launch_bounds__(256)
void edge_reorder(const float* __restrict__ rij, const float* __restrict__ vij,
                  const int* __restrict__ src, const int* __restrict__ dst,
                  int* __restrict__ cursor, float4* __restrict__ recs) {
  const int e = blockIdx.x * 256 + threadIdx.x;
  if (e >= E_EDGES) return;
  const float r = rij[e];
  if (r >= CUTOFF) return;
  const float c = 0.5f * (cosf(r * (PI_F / CUTOFF)) + 1.0f);
  const int pos = atomicAdd(&cursor[dst[e]], 1);
  recs[pos] = make_float4(c * vij[3 * e + 0], c * vij[3 * e + 1],
                          c * vij[3 * e + 2], __int_as_float(src[e]));
}

// ---------------------------------------------------------------------------
// Gather + cross + mix: 32 lanes per node (one per d). 4-edge batches to
// break the rec->q dependent-load chain; qq is (q,q2) interleaved float2.
// ---------------------------------------------------------------------------
__global__ __launch_bounds__(256)
void gather_out(const int* __restrict__ row_start, const float4* __restrict__ recs,
                const float2* __restrict__ qq,
                const float* __restrict__ w_mix, const float* __restrict__ b_mix,
                float* __restrict__ out) {
  const int tid = blockIdx.x * 256 + threadIdx.x;  // = n*32 + d
  const int n = tid >> 5;
  const int d = tid & 31;
  if (n >= N_NODES) return;

  const int s0 = row_start[n];
  const int s1 = row_start[n + 1];

  float ax = 0.f, ay = 0.f, az = 0.f, bx = 0.f, by = 0.f, bz = 0.f;
  for (int i = s0; i < s1; i += 4) {
    const int i1 = min(i + 1, s1 - 1);
    const int i2 = min(i + 2, s1 - 1);
    const int i3 = min(i + 3, s1 - 1);
    float4 rc0 = recs[i];
    float4 rc1 = recs[i1];
    float4 rc2 = recs[i2];
    float4 rc3 = recs[i3];
    float2 p0 = qq[__float_as_int(rc0.w) * 32 + d];
    float2 p1 = qq[__float_as_int(rc1.w) * 32 + d];
    float2 p2 = qq[__float_as_int(rc2.w) * 32 + d];
    float2 p3 = qq[__float_as_int(rc3.w) * 32 + d];
    const float m1 = (i + 1 < s1) ? 1.f : 0.f;
    const float m2 = (i + 2 < s1) ? 1.f : 0.f;
    const float m3 = (i + 3 < s1) ? 1.f : 0.f;
    p1.x *= m1; p1.y *= m1;
    p2.x *= m2; p2.y *= m2;
    p3.x *= m3; p3.y *= m3;

    ax += rc0.x * p0.x + rc1.x * p1.x + rc2.x * p2.x + rc3.x * p3.x;
    ay += rc0.y * p0.x + rc1.y * p1.x + rc2.y * p2.x + rc3.y * p3.x;
    az += rc0.z * p0.x + rc1.z * p1.x + rc2.z * p2.x + rc3.z * p3.x;
    bx += rc0.x * p0.y + rc1.x * p1.y + rc2.x * p2.y + rc3.x * p3.y;
    by += rc0.y * p0.y + rc1.y * p1.y + rc2.y * p2.y + rc3.y * p3.y;
    bz += rc0.z * p0.y + rc1.z * p1.y + rc2.z * p2.y + rc3.z * p3.y;
  }

  const float cx = ay * bz - az * by;
  const float cy = az * bx - ax * bz;
  const float cz = ax * by - ay * bx;

  const float w0 = w_mix[0], w1 = w_mix[1], w2 = w_mix[2];
  const float bm = b_mix[0];

  const size_t base = (size_t)tid * 3;
  out[base + 0] = ax * w0 + bx * w1 + cx * w2 + bm;
  out[base + 1] = ay * w0 + by * w1 + cy * w2 + bm;
  out[base + 2] = az * w0 + bz * w1 + cz * w2 + bm;
}

// ---------------------------------------------------------------------------
extern "C" void kernel_launch(void* const* d_in, const int* in_sizes, int n_in,
                              void* d_out, int out_size, void* d_ws, size_t ws_size,
                              hipStream_t stream) {
  const float* x     = (const float*)d_in[0];
  const float* rij   = (const float*)d_in[1];
  const float* vij   = (const float*)d_in[2];
  const int*   src   = (const int*)  d_in[3];
  const int*   dst   = (const int*)  d_in[4];
  const float* W1    = (const float*)d_in[5];
  const float* b1    = (const float*)d_in[6];
  const float* W2    = (const float*)d_in[7];
  const float* b2    = (const float*)d_in[8];
  const float* W1b   = (const float*)d_in[9];
  const float* b1b   = (const float*)d_in[10];
  const float* W2b   = (const float*)d_in[11];
  const float* b2b   = (const float*)d_in[12];
  const float* w_mix = (const float*)d_in[13];
  const float* b_mix = (const float*)d_in[14];
  float* out = (float*)d_out;

  // Workspace: recs [E f4] | qq [N*64] | deg [N] | cursor [N] | row_start [N+1] | part [256]
  float4* recs   = (float4*)d_ws;
  float* qq      = (float*)(recs + E_EDGES);
  int* deg       = (int*)(qq + (size_t)N_NODES * 64);
  int* cursor    = deg + N_NODES;
  int* row_start = cursor + N_NODES;
  int* part      = row_start + N_NODES + 1;

  hipMemsetAsync(deg, 0, sizeof(int) * N_NODES, stream);

  dim3 mlp_grid((N_NODES + 31) / 32, 2);
  node_mlp_fused<<<mlp_grid, 256, 0, stream>>>(
      x, W1, b1, W2, b2, W1b, b1b, W2b, b2b, qq);

  const int eb = (E_EDGES + 255) / 256;
  edge_hist<<<eb, 256, 0, stream>>>(rij, dst, deg);
  scan_blocksum<<<SCAN_BLOCKS, 256, 0, stream>>>(deg, part);
  scan_partials<<<1, 256, 0, stream>>>(part, row_start);
  scan_write<<<SCAN_BLOCKS, 256, 0, stream>>>(deg, part, row_start, cursor);
  edge_reorder<<<eb, 256, 0, stream>>>(rij, vij, src, dst, cursor, recs);

  gather_out<<<(N_NODES * D_DIM) / 256, 256, 0, stream>>>(
      row_start, recs, (const float2*)qq, w_mix, b_mix, out);
}